// Round 9
// baseline (740.240 us; speedup 1.0000x reference)
//
#include <hip/hip_runtime.h>
#include <hip/hip_bf16.h>
#include <stdint.h>

#define B_  2
#define S_  4096
#define D_  768
#define H_  12
#define DH_ 64
#define BS_ (B_*S_)   // 8192

typedef __bf16 bf16x8 __attribute__((ext_vector_type(8)));
typedef short  svec8  __attribute__((ext_vector_type(8)));
typedef float  fvec4  __attribute__((ext_vector_type(4)));
typedef unsigned short ushort_t;

__device__ __forceinline__ ushort_t f2bf(float f){
    unsigned u = __builtin_bit_cast(unsigned, f);
    unsigned r = (u + 0x7fffu + ((u >> 16) & 1u)) >> 16;
    return (ushort_t)r;
}

__device__ __forceinline__ fvec4 mfma16(svec8 a, svec8 b, fvec4 c){
    return __builtin_amdgcn_mfma_f32_16x16x32_bf16(
        __builtin_bit_cast(bf16x8, a), __builtin_bit_cast(bf16x8, b), c, 0, 0, 0);
}

// ---------------- QKV projection (R8-passed, verbatim) ----------------
__global__ __launch_bounds__(256) void qkv_proj(
    const float* __restrict__ X,
    const float* __restrict__ Wq, const float* __restrict__ Wk, const float* __restrict__ Wv,
    ushort_t* __restrict__ Qb, ushort_t* __restrict__ Kb, ushort_t* __restrict__ Vg)
{
    const int m0 = blockIdx.x * 128;
    const int h  = blockIdx.y;
    const int wt = blockIdx.z;
    const float* W  = (wt == 0) ? Wq : (wt == 1) ? Wk : Wv;
    const float* Wh = W + (size_t)h * (D_ * DH_);
    const float oscale = (wt == 0) ? 0.18033688011112042f : 1.0f;  // 1/8 * log2(e) on Q

    __shared__ ushort_t smem[128 * 72 + 64 * 64];
    ushort_t* Xs  = smem;
    ushort_t* Wts = smem + 128 * 72;
    ushort_t* XsT = smem;              // 64 x 136 overlay, used after K-loop

    const int tid  = threadIdx.x;
    const int w    = tid >> 6;
    const int lane = tid & 63;
    const int quad = lane >> 4;
    const int l15  = lane & 15;

    fvec4 acc[2][4];
    #pragma unroll
    for (int i = 0; i < 2; i++)
        #pragma unroll
        for (int j = 0; j < 4; j++) acc[i][j] = (fvec4){0.f, 0.f, 0.f, 0.f};

    for (int k0 = 0; k0 < D_; k0 += 64) {
        #pragma unroll
        for (int i = 0; i < 4; i++) {
            int v = tid + 256 * i;
            int r = v >> 3, c = (v & 7) * 8;
            const float* src = X + (size_t)(m0 + r) * D_ + k0 + c;
            float4 d0 = *(const float4*)(src);
            float4 d1 = *(const float4*)(src + 4);
            svec8 pk;
            pk[0] = (short)f2bf(d0.x); pk[1] = (short)f2bf(d0.y);
            pk[2] = (short)f2bf(d0.z); pk[3] = (short)f2bf(d0.w);
            pk[4] = (short)f2bf(d1.x); pk[5] = (short)f2bf(d1.y);
            pk[6] = (short)f2bf(d1.z); pk[7] = (short)f2bf(d1.w);
            *(svec8*)(Xs + r * 72 + c) = pk;
        }
        #pragma unroll
        for (int i = 0; i < 4; i++) {
            int v = tid + 256 * i;
            int k = v >> 4, t = v & 15;
            float4 d = *(const float4*)(Wh + (size_t)(k0 + k) * DH_ + t * 4);
            #pragma unroll
            for (int j = 0; j < 4; j++) {
                int n = t * 4 + j;
                int addr = n * 64 + ((((k >> 3) ^ (t & 7))) << 3) + (k & 7);
                Wts[addr] = f2bf(j == 0 ? d.x : j == 1 ? d.y : j == 2 ? d.z : d.w);
            }
        }
        __syncthreads();

        #pragma unroll
        for (int ks = 0; ks < 2; ks++) {
            svec8 a0 = *(const svec8*)(Xs + (32 * w + l15) * 72 + ks * 32 + quad * 8);
            svec8 a1 = *(const svec8*)(Xs + (32 * w + 16 + l15) * 72 + ks * 32 + quad * 8);
            #pragma unroll
            for (int ns = 0; ns < 4; ns++) {
                int n = ns * 16 + l15;
                int swz = (ks * 4 + quad) ^ ((n >> 2) & 7);
                svec8 b = *(const svec8*)(Wts + n * 64 + swz * 8);
                acc[0][ns] = mfma16(a0, b, acc[0][ns]);
                acc[1][ns] = mfma16(a1, b, acc[1][ns]);
            }
        }
        __syncthreads();
    }

    if (wt != 2) {
        ushort_t* Out = (wt == 0) ? Qb : Kb;
        #pragma unroll
        for (int ms = 0; ms < 2; ms++)
            #pragma unroll
            for (int ns = 0; ns < 4; ns++)
                #pragma unroll
                for (int r = 0; r < 4; r++) {
                    int row = m0 + 32 * w + ms * 16 + quad * 4 + r;
                    int col = h * DH_ + ns * 16 + l15;
                    Out[(size_t)row * D_ + col] = f2bf(acc[ms][ns][r] * oscale);
                }
    } else {
        #pragma unroll
        for (int ms = 0; ms < 2; ms++)
            #pragma unroll
            for (int ns = 0; ns < 4; ns++)
                #pragma unroll
                for (int r = 0; r < 4; r++) {
                    int sl = 32 * w + ms * 16 + quad * 4 + r;
                    int e  = ns * 16 + l15;
                    XsT[e * 136 + sl] = f2bf(acc[ms][ns][r]);
                }
        __syncthreads();
        #pragma unroll
        for (int i = 0; i < 4; i++) {
            int v = tid + 256 * i;
            int e = v >> 4, s0 = (v & 15) * 8;
            svec8 d = *(const svec8*)(XsT + e * 136 + s0);
            *(svec8*)(Vg + (size_t)(h * DH_ + e) * BS_ + m0 + s0) = d;
        }
    }
}

// ---------------- causal flash attention: K/V fragments direct from global ----------
// grid (64 q-tiles, 12 heads, 2 batches), 256 threads (4 waves); wave owns 16 q-rows.
// No LDS for K/V (fragments are contiguous 16B runs in Kb / pre-transposed Vg; all 4
// waves read identical addresses -> L1 hits). No __syncthreads anywhere. LDS = P only.
__global__ __launch_bounds__(256) void attn(
    const ushort_t* __restrict__ Qb, const ushort_t* __restrict__ Kb,
    const ushort_t* __restrict__ Vg, float* __restrict__ Out)
{
    const int qt = gridDim.x - 1 - blockIdx.x;   // long blocks first
    const int h  = blockIdx.y;
    const int b  = blockIdx.z;
    const int q0 = qt * 64;

    const int tid  = threadIdx.x;
    const int w    = tid >> 6;
    const int lane = tid & 63;
    const int quad = lane >> 4;
    const int l15  = lane & 15;

    __shared__ ushort_t Ps[4 * 16 * 72];   // wave-private P staging only (9216 B)
    ushort_t* Pw = Ps + w * 16 * 72;

    const size_t hb = (size_t)b * S_ * D_ + (size_t)h * DH_;
    const ushort_t* Vh = Vg + (size_t)h * DH_ * BS_ + (size_t)b * S_;

    // per-lane K/V fragment base pointers (advance by kt inside the loop)
    // bk(n,ks) = Kb[hb + (kt*64 + n*16+l15)*D + ks*32 + quad*8], 8 contiguous e
    // bv(n,ks) = Vh[(n*16+l15)*BS + kt*64 + ks*32 + quad*8],     8 contiguous keys
    const ushort_t* kbase = Kb + hb + (size_t)l15 * D_ + quad * 8;
    const ushort_t* vbase = Vh + (size_t)l15 * BS_ + quad * 8;

    // Q fragments (pre-scaled to log2 domain in qkv_proj)
    svec8 aq[2];
    {
        const ushort_t* qrow = Qb + hb + (size_t)(q0 + 16 * w + l15) * D_;
        aq[0] = *(const svec8*)(qrow + quad * 8);
        aq[1] = *(const svec8*)(qrow + 32 + quad * 8);
    }

    float m_i = -INFINITY;
    float ls[4] = {0.f, 0.f, 0.f, 0.f};   // per-lane partial denominators
    fvec4 acc[4];
    #pragma unroll
    for (int n = 0; n < 4; n++) acc[n] = (fvec4){0.f, 0.f, 0.f, 0.f};

    for (int kt = 0; kt <= qt; ++kt) {
        // S = Q K^T (log2 domain via pre-scaled Q) — fragments straight from global
        fvec4 s[4];
        #pragma unroll
        for (int n = 0; n < 4; n++) s[n] = (fvec4){0.f, 0.f, 0.f, 0.f};
        #pragma unroll
        for (int ks = 0; ks < 2; ks++)
            #pragma unroll
            for (int n = 0; n < 4; n++) {
                svec8 bk = *(const svec8*)(kbase + (size_t)(kt * 64 + n * 16) * D_ + ks * 32);
                s[n] = mfma16(aq[ks], bk, s[n]);
            }

        // causal mask on the diagonal tile
        if (kt == qt) {
            #pragma unroll
            for (int n = 0; n < 4; n++)
                #pragma unroll
                for (int r = 0; r < 4; r++) {
                    int col = n * 16 + l15;
                    int row = 16 * w + quad * 4 + r;
                    if (col > row) s[n][r] = -INFINITY;
                }
        }

        // wave-uniform max: in-lane tree over 16, then one 6-deep shuffle chain
        float mx = fmaxf(fmaxf(fmaxf(s[0][0], s[0][1]), fmaxf(s[0][2], s[0][3])),
                         fmaxf(fmaxf(s[1][0], s[1][1]), fmaxf(s[1][2], s[1][3])));
        float mx2 = fmaxf(fmaxf(fmaxf(s[2][0], s[2][1]), fmaxf(s[2][2], s[2][3])),
                          fmaxf(fmaxf(s[3][0], s[3][1]), fmaxf(s[3][2], s[3][3])));
        mx = fmaxf(mx, mx2);
        mx = fmaxf(mx, __shfl_xor(mx, 1));
        mx = fmaxf(mx, __shfl_xor(mx, 2));
        mx = fmaxf(mx, __shfl_xor(mx, 4));
        mx = fmaxf(mx, __shfl_xor(mx, 8));
        mx = fmaxf(mx, __shfl_xor(mx, 16));
        mx = fmaxf(mx, __shfl_xor(mx, 32));
        float mn = fmaxf(m_i, mx);
        float alpha = exp2f(m_i - mn);
        m_i = mn;

        // p = exp2(s - m); per-lane partial sums; stage P to wave-private LDS
        #pragma unroll
        for (int r = 0; r < 4; r++) ls[r] *= alpha;
        #pragma unroll
        for (int n = 0; n < 4; n++)
            #pragma unroll
            for (int r = 0; r < 4; r++) {
                float p = exp2f(s[n][r] - mn);
                ls[r] += p;
                Pw[(quad * 4 + r) * 72 + n * 16 + l15] = f2bf(p);
            }
        #pragma unroll
        for (int n = 0; n < 4; n++)
            #pragma unroll
            for (int r = 0; r < 4; r++) acc[n][r] *= alpha;

        // wave-private visibility: drain LDS queue (DS ops complete in order)
        asm volatile("s_waitcnt lgkmcnt(0)" ::: "memory");

        // O += P V — V fragments straight from global (pre-transposed Vg)
        #pragma unroll
        for (int ks = 0; ks < 2; ks++) {
            svec8 ap = *(const svec8*)(Pw + l15 * 72 + ks * 32 + quad * 8);
            #pragma unroll
            for (int n = 0; n < 4; n++) {
                svec8 bv = *(const svec8*)(vbase + (size_t)(n * 16) * BS_ + kt * 64 + ks * 32);
                acc[n] = mfma16(ap, bv, acc[n]);
            }
        }
    }

    // epilogue: reduce per-lane denominators across the 16 lanes of each row, divide, store
    float l_i[4];
    #pragma unroll
    for (int r = 0; r < 4; r++) {
        float v = ls[r];
        v += __shfl_xor(v, 1, 16);
        v += __shfl_xor(v, 2, 16);
        v += __shfl_xor(v, 4, 16);
        v += __shfl_xor(v, 8, 16);
        l_i[r] = v;
    }
    #pragma unroll
    for (int n = 0; n < 4; n++)
        #pragma unroll
        for (int r = 0; r < 4; r++) {
            int row = q0 + 16 * w + quad * 4 + r;
            int col = h * DH_ + n * 16 + l15;
            Out[((size_t)b * S_ + row) * D_ + col] = acc[n][r] / l_i[r];
        }
}

extern "C" void kernel_launch(void* const* d_in, const int* in_sizes, int n_in,
                              void* d_out, int out_size, void* d_ws, size_t ws_size,
                              hipStream_t stream)
{
    const float* X  = (const float*)d_in[0];
    const float* Wq = (const float*)d_in[1];
    const float* Wk = (const float*)d_in[2];
    const float* Wv = (const float*)d_in[3];

    ushort_t* Qb = (ushort_t*)d_ws;                      // 8192*768 bf16 (pre-scaled)
    ushort_t* Kb = Qb + (size_t)BS_ * D_;                // 8192*768 bf16
    ushort_t* Vg = Kb + (size_t)BS_ * D_;                // [768][8192] bf16 transposed
    float* Out = (float*)d_out;

    qkv_proj<<<dim3(64, H_, 3), dim3(256), 0, stream>>>(X, Wq, Wk, Wv, Qb, Kb, Vg);
    attn<<<dim3(S_ / 64, H_, B_), dim3(256), 0, stream>>>(Qb, Kb, Vg, Out);
}

// Round 10
// 384.802 us; speedup vs baseline: 1.9237x; 1.9237x over previous
//
#include <hip/hip_runtime.h>
#include <hip/hip_bf16.h>
#include <stdint.h>

#define B_  2
#define S_  4096
#define D_  768
#define H_  12
#define DH_ 64
#define BS_ (B_*S_)   // 8192

typedef __bf16 bf16x8 __attribute__((ext_vector_type(8)));
typedef short  svec8  __attribute__((ext_vector_type(8)));
typedef float  fvec4  __attribute__((ext_vector_type(4)));
typedef unsigned short ushort_t;

__device__ __forceinline__ ushort_t f2bf(float f){
    unsigned u = __builtin_bit_cast(unsigned, f);
    unsigned r = (u + 0x7fffu + ((u >> 16) & 1u)) >> 16;
    return (ushort_t)r;
}

__device__ __forceinline__ fvec4 mfma16(svec8 a, svec8 b, fvec4 c){
    return __builtin_amdgcn_mfma_f32_16x16x32_bf16(
        __builtin_bit_cast(bf16x8, a), __builtin_bit_cast(bf16x8, b), c, 0, 0, 0);
}

// ---------------- QKV projection (R8-passed, verbatim) ----------------
__global__ __launch_bounds__(256) void qkv_proj(
    const float* __restrict__ X,
    const float* __restrict__ Wq, const float* __restrict__ Wk, const float* __restrict__ Wv,
    ushort_t* __restrict__ Qb, ushort_t* __restrict__ Kb, ushort_t* __restrict__ Vg)
{
    const int m0 = blockIdx.x * 128;
    const int h  = blockIdx.y;
    const int wt = blockIdx.z;
    const float* W  = (wt == 0) ? Wq : (wt == 1) ? Wk : Wv;
    const float* Wh = W + (size_t)h * (D_ * DH_);
    const float oscale = (wt == 0) ? 0.18033688011112042f : 1.0f;  // 1/8 * log2(e) on Q

    __shared__ ushort_t smem[128 * 72 + 64 * 64];
    ushort_t* Xs  = smem;
    ushort_t* Wts = smem + 128 * 72;
    ushort_t* XsT = smem;              // 64 x 136 overlay, used after K-loop

    const int tid  = threadIdx.x;
    const int w    = tid >> 6;
    const int lane = tid & 63;
    const int quad = lane >> 4;
    const int l15  = lane & 15;

    fvec4 acc[2][4];
    #pragma unroll
    for (int i = 0; i < 2; i++)
        #pragma unroll
        for (int j = 0; j < 4; j++) acc[i][j] = (fvec4){0.f, 0.f, 0.f, 0.f};

    for (int k0 = 0; k0 < D_; k0 += 64) {
        #pragma unroll
        for (int i = 0; i < 4; i++) {
            int v = tid + 256 * i;
            int r = v >> 3, c = (v & 7) * 8;
            const float* src = X + (size_t)(m0 + r) * D_ + k0 + c;
            float4 d0 = *(const float4*)(src);
            float4 d1 = *(const float4*)(src + 4);
            svec8 pk;
            pk[0] = (short)f2bf(d0.x); pk[1] = (short)f2bf(d0.y);
            pk[2] = (short)f2bf(d0.z); pk[3] = (short)f2bf(d0.w);
            pk[4] = (short)f2bf(d1.x); pk[5] = (short)f2bf(d1.y);
            pk[6] = (short)f2bf(d1.z); pk[7] = (short)f2bf(d1.w);
            *(svec8*)(Xs + r * 72 + c) = pk;
        }
        #pragma unroll
        for (int i = 0; i < 4; i++) {
            int v = tid + 256 * i;
            int k = v >> 4, t = v & 15;
            float4 d = *(const float4*)(Wh + (size_t)(k0 + k) * DH_ + t * 4);
            #pragma unroll
            for (int j = 0; j < 4; j++) {
                int n = t * 4 + j;
                int addr = n * 64 + ((((k >> 3) ^ (t & 7))) << 3) + (k & 7);
                Wts[addr] = f2bf(j == 0 ? d.x : j == 1 ? d.y : j == 2 ? d.z : d.w);
            }
        }
        __syncthreads();

        #pragma unroll
        for (int ks = 0; ks < 2; ks++) {
            svec8 a0 = *(const svec8*)(Xs + (32 * w + l15) * 72 + ks * 32 + quad * 8);
            svec8 a1 = *(const svec8*)(Xs + (32 * w + 16 + l15) * 72 + ks * 32 + quad * 8);
            #pragma unroll
            for (int ns = 0; ns < 4; ns++) {
                int n = ns * 16 + l15;
                int swz = (ks * 4 + quad) ^ ((n >> 2) & 7);
                svec8 b = *(const svec8*)(Wts + n * 64 + swz * 8);
                acc[0][ns] = mfma16(a0, b, acc[0][ns]);
                acc[1][ns] = mfma16(a1, b, acc[1][ns]);
            }
        }
        __syncthreads();
    }

    if (wt != 2) {
        ushort_t* Out = (wt == 0) ? Qb : Kb;
        #pragma unroll
        for (int ms = 0; ms < 2; ms++)
            #pragma unroll
            for (int ns = 0; ns < 4; ns++)
                #pragma unroll
                for (int r = 0; r < 4; r++) {
                    int row = m0 + 32 * w + ms * 16 + quad * 4 + r;
                    int col = h * DH_ + ns * 16 + l15;
                    Out[(size_t)row * D_ + col] = f2bf(acc[ms][ns][r] * oscale);
                }
    } else {
        #pragma unroll
        for (int ms = 0; ms < 2; ms++)
            #pragma unroll
            for (int ns = 0; ns < 4; ns++)
                #pragma unroll
                for (int r = 0; r < 4; r++) {
                    int sl = 32 * w + ms * 16 + quad * 4 + r;
                    int e  = ns * 16 + l15;
                    XsT[e * 136 + sl] = f2bf(acc[ms][ns][r]);
                }
        __syncthreads();
        #pragma unroll
        for (int i = 0; i < 4; i++) {
            int v = tid + 256 * i;
            int e = v >> 4, s0 = (v & 15) * 8;
            svec8 d = *(const svec8*)(XsT + e * 136 + s0);
            *(svec8*)(Vg + (size_t)(h * DH_ + e) * BS_ + m0 + s0) = d;
        }
    }
}

// ---------------- causal flash attention (R8 softmax, single-buffer LDS, 5 blk/CU) ---
// grid (64 q-tiles, 12 heads, 2 batches), 256 threads (4 waves); wave owns 16 q-rows.
// Single-buffered K/V tiles (register prefetch, 2 barriers/iter): LDS 27648 B ->
// 5 blocks/CU (vs 3 with double-buffer) so barrier stalls are hidden by other blocks.
__global__ __launch_bounds__(256) void attn(
    const ushort_t* __restrict__ Qb, const ushort_t* __restrict__ Kb,
    const ushort_t* __restrict__ Vg, float* __restrict__ Out)
{
    const int qt = gridDim.x - 1 - blockIdx.x;   // long blocks first
    const int h  = blockIdx.y;
    const int b  = blockIdx.z;
    const int q0 = qt * 64;

    const int tid  = threadIdx.x;
    const int w    = tid >> 6;
    const int lane = tid & 63;
    const int quad = lane >> 4;
    const int l15  = lane & 15;

    __shared__ ushort_t Ks[64 * 72];       // K tile [key][e], single-buffered
    __shared__ ushort_t Vt[64 * 72];       // V^T tile [e][key], single-buffered
    __shared__ ushort_t Ps[4 * 16 * 72];   // wave-private P staging
    ushort_t* Pw = Ps + w * 16 * 72;

    const size_t hb = (size_t)b * S_ * D_ + (size_t)h * DH_;
    const ushort_t* Vh = Vg + (size_t)h * DH_ * BS_ + (size_t)b * S_;

    const int sr = tid >> 3;          // staging row 0..31 (+32)
    const int sc = (tid & 7) * 8;

    // Q fragments (pre-scaled to log2 domain in qkv_proj)
    svec8 aq[2];
    {
        const ushort_t* qrow = Qb + hb + (size_t)(q0 + 16 * w + l15) * D_;
        aq[0] = *(const svec8*)(qrow + quad * 8);
        aq[1] = *(const svec8*)(qrow + 32 + quad * 8);
    }

    float m_i = -INFINITY;
    float ls[4] = {0.f, 0.f, 0.f, 0.f};   // per-lane partial denominators
    fvec4 acc[4];
    #pragma unroll
    for (int n = 0; n < 4; n++) acc[n] = (fvec4){0.f, 0.f, 0.f, 0.f};

    // prologue: stage tile 0
    svec8 kd[2], vd[2];
    #pragma unroll
    for (int i = 0; i < 2; i++) {
        int r = sr + 32 * i;
        kd[i] = *(const svec8*)(Kb + hb + (size_t)r * D_ + sc);
        vd[i] = *(const svec8*)(Vh + (size_t)r * BS_ + sc);
    }
    #pragma unroll
    for (int i = 0; i < 2; i++) {
        int r = sr + 32 * i;
        *(svec8*)(Ks + r * 72 + sc) = kd[i];
        *(svec8*)(Vt + r * 72 + sc) = vd[i];
    }

    for (int kt = 0; kt <= qt; ++kt) {
        __syncthreads();   // staged tile kt visible to all waves

        // prefetch next tile into registers (in flight across the compute phase)
        if (kt < qt) {
            #pragma unroll
            for (int i = 0; i < 2; i++) {
                int r = sr + 32 * i;
                kd[i] = *(const svec8*)(Kb + hb + (size_t)((kt + 1) * 64 + r) * D_ + sc);
                vd[i] = *(const svec8*)(Vh + (size_t)r * BS_ + (kt + 1) * 64 + sc);
            }
        }

        // S = Q K^T (log2 domain via pre-scaled Q)
        fvec4 s[4];
        #pragma unroll
        for (int n = 0; n < 4; n++) s[n] = (fvec4){0.f, 0.f, 0.f, 0.f};
        #pragma unroll
        for (int ks = 0; ks < 2; ks++)
            #pragma unroll
            for (int n = 0; n < 4; n++) {
                svec8 bk = *(const svec8*)(Ks + (n * 16 + l15) * 72 + ks * 32 + quad * 8);
                s[n] = mfma16(aq[ks], bk, s[n]);
            }

        // causal mask on the diagonal tile
        if (kt == qt) {
            #pragma unroll
            for (int n = 0; n < 4; n++)
                #pragma unroll
                for (int r = 0; r < 4; r++) {
                    int col = n * 16 + l15;
                    int row = 16 * w + quad * 4 + r;
                    if (col > row) s[n][r] = -INFINITY;
                }
        }

        // wave-uniform max: in-lane tree over 16, then one 6-deep shuffle chain
        float mx = fmaxf(fmaxf(fmaxf(s[0][0], s[0][1]), fmaxf(s[0][2], s[0][3])),
                         fmaxf(fmaxf(s[1][0], s[1][1]), fmaxf(s[1][2], s[1][3])));
        float mx2 = fmaxf(fmaxf(fmaxf(s[2][0], s[2][1]), fmaxf(s[2][2], s[2][3])),
                          fmaxf(fmaxf(s[3][0], s[3][1]), fmaxf(s[3][2], s[3][3])));
        mx = fmaxf(mx, mx2);
        mx = fmaxf(mx, __shfl_xor(mx, 1));
        mx = fmaxf(mx, __shfl_xor(mx, 2));
        mx = fmaxf(mx, __shfl_xor(mx, 4));
        mx = fmaxf(mx, __shfl_xor(mx, 8));
        mx = fmaxf(mx, __shfl_xor(mx, 16));
        mx = fmaxf(mx, __shfl_xor(mx, 32));
        float mn = fmaxf(m_i, mx);
        float alpha = exp2f(m_i - mn);
        m_i = mn;

        // p = exp2(s - m); per-lane partial sums; stage P (truncation-to-bf16: cheap,
        // p in [0,1] so rel err <= 2^-8 — well under the 2% threshold)
        #pragma unroll
        for (int r = 0; r < 4; r++) ls[r] *= alpha;
        #pragma unroll
        for (int n = 0; n < 4; n++)
            #pragma unroll
            for (int r = 0; r < 4; r++) {
                float p = exp2f(s[n][r] - mn);
                ls[r] += p;
                Pw[(quad * 4 + r) * 72 + n * 16 + l15] =
                    (ushort_t)(__builtin_bit_cast(unsigned, p) >> 16);
            }
        #pragma unroll
        for (int n = 0; n < 4; n++)
            #pragma unroll
            for (int r = 0; r < 4; r++) acc[n][r] *= alpha;

        // wave-private visibility: drain LDS queue (DS ops complete in order)
        asm volatile("s_waitcnt lgkmcnt(0)" ::: "memory");

        // O += P V
        #pragma unroll
        for (int ks = 0; ks < 2; ks++) {
            svec8 ap = *(const svec8*)(Pw + l15 * 72 + ks * 32 + quad * 8);
            #pragma unroll
            for (int n = 0; n < 4; n++) {
                svec8 bv = *(const svec8*)(Vt + (n * 16 + l15) * 72 + ks * 32 + quad * 8);
                acc[n] = mfma16(ap, bv, acc[n]);
            }
        }

        __syncthreads();   // all waves done reading tile kt

        if (kt < qt) {
            #pragma unroll
            for (int i = 0; i < 2; i++) {
                int r = sr + 32 * i;
                *(svec8*)(Ks + r * 72 + sc) = kd[i];
                *(svec8*)(Vt + r * 72 + sc) = vd[i];
            }
        }
    }

    // epilogue: reduce per-lane denominators across the 16 lanes of each row, divide, store
    float l_i[4];
    #pragma unroll
    for (int r = 0; r < 4; r++) {
        float v = ls[r];
        v += __shfl_xor(v, 1, 16);
        v += __shfl_xor(v, 2, 16);
        v += __shfl_xor(v, 4, 16);
        v += __shfl_xor(v, 8, 16);
        l_i[r] = v;
    }
    #pragma unroll
    for (int n = 0; n < 4; n++)
        #pragma unroll
        for (int r = 0; r < 4; r++) {
            int row = q0 + 16 * w + quad * 4 + r;
            int col = h * DH_ + n * 16 + l15;
            Out[((size_t)b * S_ + row) * D_ + col] = acc[n][r] / l_i[r];
        }
}

extern "C" void kernel_launch(void* const* d_in, const int* in_sizes, int n_in,
                              void* d_out, int out_size, void* d_ws, size_t ws_size,
                              hipStream_t stream)
{
    const float* X  = (const float*)d_in[0];
    const float* Wq = (const float*)d_in[1];
    const float* Wk = (const float*)d_in[2];
    const float* Wv = (const float*)d_in[3];

    ushort_t* Qb = (ushort_t*)d_ws;                      // 8192*768 bf16 (pre-scaled)
    ushort_t* Kb = Qb + (size_t)BS_ * D_;                // 8192*768 bf16
    ushort_t* Vg = Kb + (size_t)BS_ * D_;                // [768][8192] bf16 transposed
    float* Out = (float*)d_out;

    qkv_proj<<<dim3(64, H_, 3), dim3(256), 0, stream>>>(X, Wq, Wk, Wv, Qb, Kb, Vg);
    attn<<<dim3(S_ / 64, H_, B_), dim3(256), 0, stream>>>(Qb, Kb, Vg, Out);
}